// Round 12
// baseline (129.758 us; speedup 1.0000x reference)
//
#include <hip/hip_runtime.h>
#include <stdint.h>

#define B_  2
#define S_  2048
#define D_  1024
#define H_  16
#define DK_ 64

using bf16x8 = __attribute__((ext_vector_type(8))) short;
using f32x4  = __attribute__((ext_vector_type(4))) float;

__device__ __forceinline__ unsigned short f2bf(float f) {
    union { float f; uint32_t u; } v; v.f = f;
    uint32_t r = v.u + 0x7FFFu + ((v.u >> 16) & 1u);
    return (unsigned short)(r >> 16);
}

// pack two f32 -> one u32 of two bf16 (low = s0), RNE in HW
__device__ __forceinline__ uint32_t cvtpk(float lo, float hi) {
    uint32_t r;
    asm("v_cvt_pk_bf16_f32 %0, %1, %2" : "=v"(r) : "v"(lo), "v"(hi));
    return r;
}
// a' = {a(0-31), b(0-31)} ; b' = {a(32-63), b(32-63)}
__device__ __forceinline__ void ps32(uint32_t& a, uint32_t& b) {
    asm volatile("v_permlane32_swap_b32 %0, %1" : "+v"(a), "+v"(b));
}
// 16-lane rows: odd rows of a <-> even rows of b
__device__ __forceinline__ void ps16(uint32_t& a, uint32_t& b) {
    asm volatile("v_permlane16_swap_b32 %0, %1" : "+v"(a), "+v"(b));
}

// async global->LDS, 16B per lane; LDS dest is wave-uniform base + lane*16
#define GLD16(G, L) __builtin_amdgcn_global_load_lds( \
    (const __attribute__((address_space(1))) void*)(const void*)(G), \
    (__attribute__((address_space(3))) void*)(void*)(L), 16, 0, 0)

// ---------------- unified prep: x->bf16, 4 weights->bf16, trig table -------
// grid 8448: [0,4096) x-convert, [4096,8192) weights, [8192,8448) trig table
__global__ __launch_bounds__(256) void k_prep(
    const float* __restrict__ x,
    const float* __restrict__ Wq, const float* __restrict__ Wk,
    const float* __restrict__ Wv, const float* __restrict__ Wo,
    unsigned short* __restrict__ xb,
    unsigned short* __restrict__ wqb, unsigned short* __restrict__ wkb,
    unsigned short* __restrict__ wvb, unsigned short* __restrict__ wob,
    float2* __restrict__ trig)
{
    const int bid = blockIdx.x, tid = threadIdx.x;
    if (bid < 4096) {
        const int i = bid * 256 + tid;
        float4 v = ((const float4*)x)[i];
        union { unsigned short u[4]; uint2 d; } o;
        o.u[0] = f2bf(v.x); o.u[1] = f2bf(v.y); o.u[2] = f2bf(v.z); o.u[3] = f2bf(v.w);
        ((uint2*)xb)[i] = o.d;
    } else if (bid < 8192) {
        const int w = (bid - 4096) >> 10;
        const float* s = w == 0 ? Wq : w == 1 ? Wk : w == 2 ? Wv : Wo;
        unsigned short* d = w == 0 ? wqb : w == 1 ? wkb : w == 2 ? wvb : wob;
        const int i = ((bid - 4096) & 1023) * 256 + tid;
        float4 v = ((const float4*)s)[i];
        union { unsigned short u[4]; uint2 dd; } o;
        o.u[0] = f2bf(v.x); o.u[1] = f2bf(v.y); o.u[2] = f2bf(v.z); o.u[3] = f2bf(v.w);
        ((uint2*)d)[i] = o.dd;
    } else {
        const int idx = (bid - 8192) * 256 + tid;   // [0, 65536)
        const int p = idx & 31, pos = idx >> 5;
        const float inv = exp2f((float)(-2 * p) * (13.287712379549449f / 64.f)); // 10000^(-2p/64)
        float sn, cs;
        sincosf((float)pos * inv, &sn, &cs);
        trig[idx] = make_float2(cs, sn);
    }
}

// ---------------- GEMM: C[m][n] = sum_k A[m][k] * W[n][k]  (B^T input) ------
// conflict-free XOR swizzle (both-sides) + 2-phase prefetch (round-8 proven).
// MODE 0: bf16 out. z=0 (Q), z=1 (K): [b][h][s][dk] head layout, with RoPE
//                   FUSED in the f32 epilogue (pair via __shfl_xor(1), trig
//                   from precomputed table). z=2 (V): transposed [b][h][dk][s].
// MODE 1: f32 out, row-major [m][n] (final output projection)
template<int MODE>
__global__ __launch_bounds__(256) void k_gemm_bt(
    const unsigned short* __restrict__ A,
    const unsigned short* __restrict__ W0,
    const unsigned short* __restrict__ W1,
    const unsigned short* __restrict__ W2,
    void* __restrict__ C0, void* __restrict__ C1, void* __restrict__ C2,
    int M, int N, int K,
    const int* __restrict__ tok, const float2* __restrict__ trig)
{
    __shared__ __align__(16) unsigned short As[2][128 * 32];
    __shared__ __align__(16) unsigned short Bs[2][128 * 32];

    const int tid  = threadIdx.x;
    const int wid  = tid >> 6, lane = tid & 63;
    const int m16  = lane & 15, g = lane >> 4;
    const int m0   = blockIdx.x * 128, n0 = blockIdx.y * 128;
    const unsigned short* Wm = blockIdx.z == 0 ? W0 : (blockIdx.z == 1 ? W1 : W2);
    void* Cm = blockIdx.z == 0 ? C0 : (blockIdx.z == 1 ? C1 : C2);

    const int wm = (wid >> 1) * 64, wn = (wid & 1) * 64;
    const int srow = lane >> 2;
    const int scol = ((lane & 3) ^ ((lane >> 3) & 3)) * 8;
    const int sw8  = (m16 >> 1) & 3;

    const f32x4 fz = {0.f, 0.f, 0.f, 0.f};
    f32x4 acc[4][4];
#pragma unroll
    for (int i = 0; i < 4; ++i)
#pragma unroll
        for (int j = 0; j < 4; ++j) acc[i][j] = fz;

#pragma unroll
    for (int c = 0; c < 2; ++c) {
        const int chunk = wid * 2 + c;
        const int row   = chunk * 16 + srow;
        GLD16(A  + (size_t)(m0 + row) * K + scol, &As[0][chunk * 512]);
        GLD16(Wm + (size_t)(n0 + row) * K + scol, &Bs[0][chunk * 512]);
    }
    __syncthreads();

    int buf = 0;
    for (int k0 = 0; k0 < K; k0 += 32) {
        if (k0 + 32 < K) {
#pragma unroll
            for (int c = 0; c < 2; ++c) {
                const int chunk = wid * 2 + c;
                const int row   = chunk * 16 + srow;
                GLD16(A  + (size_t)(m0 + row) * K + k0 + 32 + scol, &As[buf ^ 1][chunk * 512]);
                GLD16(Wm + (size_t)(n0 + row) * K + k0 + 32 + scol, &Bs[buf ^ 1][chunk * 512]);
            }
        }
        bf16x8 af[4], bf[4];
#pragma unroll
        for (int i = 0; i < 4; ++i)
            af[i] = *(const bf16x8*)(&As[buf][(wm + i * 16 + m16) * 32 + ((g ^ sw8) * 8)]);
#pragma unroll
        for (int j = 0; j < 4; ++j)
            bf[j] = *(const bf16x8*)(&Bs[buf][(wn + j * 16 + m16) * 32 + ((g ^ sw8) * 8)]);
#pragma unroll
        for (int i = 0; i < 4; ++i)
#pragma unroll
            for (int j = 0; j < 4; ++j)
                acc[i][j] = __builtin_amdgcn_mfma_f32_16x16x32_bf16(af[i], bf[j], acc[i][j], 0, 0, 0);
        __syncthreads();
        buf ^= 1;
    }

    const bool doRope = (MODE == 0) && (blockIdx.z < 2);
#pragma unroll
    for (int i = 0; i < 4; ++i) {
#pragma unroll
        for (int j = 0; j < 4; ++j) {
#pragma unroll
            for (int r = 0; r < 4; ++r) {
                const int row = m0 + wm + i * 16 + g * 4 + r;
                const int col = n0 + wn + j * 16 + m16;
                float val = acc[i][j][r];
                if (MODE == 1) {
                    ((float*)Cm)[(size_t)row * N + col] = val;
                } else {
                    const int b = row >> 11, s = row & (S_ - 1);
                    const int h = col >> 6,  dk = col & (DK_ - 1);
                    // fused RoPE for Q,K (f32, pre-round)
                    const float part = __shfl_xor(val, 1);   // partner dk^1
                    if (doRope) {
                        const int pos = tok[b * S_ + s];
                        const float2 cs = trig[pos * 32 + (dk >> 1)];
                        val = (dk & 1) ? (part * cs.y + val * cs.x)
                                       : (val * cs.x - part * cs.y);
                    }
                    size_t idx;
                    if (blockIdx.z == 2)   // V: transposed [bh][dk][s]
                        idx = ((size_t)((b * H_ + h) * DK_ + dk)) * S_ + s;
                    else                   // Q,K: [bh][s][dk]
                        idx = ((size_t)((b * H_ + h) * S_ + s)) * DK_ + dk;
                    ((unsigned short*)Cm)[idx] = f2bf(val);
                }
            }
        }
    }
}

// ---------------- causal flash attention v6b ----------------
// v6 (round-8 best: 16-row waves, 64-kv tiles, uniform fold j/31-j, dbuf +
// __syncthreads, permlane P, V-frag hoist) + ones-MFMA row-sum: the softmax
// denominator is accumulated by 2 extra PV MFMAs against an all-ones B
// fragment (psacc[r] = rowsum of q-row g*4+r, exactly o's C-layout) —
// removes 16 VALU adds/tile and ALL epilogue shuffles.
__global__ __launch_bounds__(256, 2) void k_fattn6b(
    const unsigned short* __restrict__ Q,   // [bh][s][64]
    const unsigned short* __restrict__ K,   // [bh][s][64]
    const unsigned short* __restrict__ Vt,  // [bh][64][2048]
    unsigned short* __restrict__ O)         // [b][s][1024] bf16
{
    __shared__ __align__(16) unsigned short Ks[2][64 * 64];
    __shared__ __align__(16) unsigned short Vs[2][64 * 64];

    const int tid = threadIdx.x, wid = tid >> 6, lane = tid & 63;
    const int m16 = lane & 15, g = lane >> 4;
    const int bh = blockIdx.x & 31;
    const int j  = blockIdx.x >> 5;                     // 0..15
    const int b = bh >> 4, h = bh & 15;
    const unsigned short* Qb = Q  + (size_t)bh * S_ * DK_;
    const unsigned short* Kb = K  + (size_t)bh * S_ * DK_;
    const unsigned short* Vb = Vt + (size_t)bh * DK_ * S_;

    const int r8   = lane >> 3;
    const int slot = (lane & 7) ^ r8;
    const int ch0  = wid * 2, ch1 = wid * 2 + 1;

    const f32x4 fz = {0.f, 0.f, 0.f, 0.f};
    const float kSc = 0.125f * 1.4426950408889634f;
    union { uint32_t u[4]; bf16x8 v; } one_;
    one_.u[0] = one_.u[1] = one_.u[2] = one_.u[3] = 0x3F803F80u;
    const bf16x8 ones = one_.v;

    GLD16(Kb + (size_t)(ch0 * 8 + r8) * DK_ + slot * 8, &Ks[0][ch0 * 512]);
    GLD16(Kb + (size_t)(ch1 * 8 + r8) * DK_ + slot * 8, &Ks[0][ch1 * 512]);
    GLD16(Vb + (size_t)(ch0 * 8 + r8) * S_  + slot * 8, &Vs[0][ch0 * 512]);
    GLD16(Vb + (size_t)(ch1 * 8 + r8) * S_  + slot * 8, &Vs[0][ch1 * 512]);
    __syncthreads();

    int buf = 0;
#pragma unroll
    for (int ph = 0; ph < 2; ++ph) {
        const int qi = ph ? 31 - j : j;
        const int q0 = qi * 64;
        const int qw0 = q0 + wid * 16;

        bf16x8 qf[2];
        {
            const unsigned short* qp = Qb + (size_t)(qw0 + m16) * DK_ + g * 8;
            qf[0] = *(const bf16x8*)(qp);
            qf[1] = *(const bf16x8*)(qp + 32);
        }

        f32x4 o[4];
#pragma unroll
        for (int i = 0; i < 4; ++i) o[i] = fz;
        f32x4 psacc = fz;               // row-sum accumulator (ones-MFMA)

        const int nt = qi + 1;
        for (int t = 0; t < nt; ++t) {
            const int kv0 = t * 64;
            int nkv0 = -1;
            if (t + 1 < nt)      nkv0 = kv0 + 64;
            else if (ph == 0)    nkv0 = 0;
            if (nkv0 >= 0) {
                GLD16(Kb + (size_t)(nkv0 + ch0 * 8 + r8) * DK_ + slot * 8, &Ks[buf ^ 1][ch0 * 512]);
                GLD16(Kb + (size_t)(nkv0 + ch1 * 8 + r8) * DK_ + slot * 8, &Ks[buf ^ 1][ch1 * 512]);
                GLD16(Vb + (size_t)(ch0 * 8 + r8) * S_ + nkv0 + slot * 8, &Vs[buf ^ 1][ch0 * 512]);
                GLD16(Vb + (size_t)(ch1 * 8 + r8) * S_ + nkv0 + slot * 8, &Vs[buf ^ 1][ch1 * 512]);
            }

            f32x4 sc[4];
            __builtin_amdgcn_s_setprio(1);
#pragma unroll
            for (int c = 0; c < 4; ++c) {
                const int row = c * 16 + m16, rr = row & 7;
                bf16x8 kf0 = *(const bf16x8*)(&Ks[buf][row * 64 + ((g ^ rr) << 3)]);
                bf16x8 kf1 = *(const bf16x8*)(&Ks[buf][row * 64 + (((4 + g) ^ rr) << 3)]);
                f32x4 z = fz;
                z = __builtin_amdgcn_mfma_f32_16x16x32_bf16(kf0, qf[0], z, 0, 0, 0);
                z = __builtin_amdgcn_mfma_f32_16x16x32_bf16(kf1, qf[1], z, 0, 0, 0);
                sc[c] = z;
            }
            __builtin_amdgcn_s_setprio(0);

            bf16x8 vf[2][4];
#pragma unroll
            for (int c2 = 0; c2 < 4; ++c2) {
                const int rv = (c2 * 16 + m16) & 7;
                vf[0][c2] = *(const bf16x8*)(&Vs[buf][(c2 * 16 + m16) * 64 + ((g ^ rv) << 3)]);
                vf[1][c2] = *(const bf16x8*)(&Vs[buf][(c2 * 16 + m16) * 64 + (((4 + g) ^ rv) << 3)]);
            }

            const bool maskT = (t == qi);
            const int qrow = qw0 + m16;
            uint32_t pk[4][2];
#pragma unroll
            for (int c = 0; c < 4; ++c) {
                float p[4];
#pragma unroll
                for (int r = 0; r < 4; ++r) {
                    float v = exp2f(sc[c][r] * kSc);
                    if (maskT && (kv0 + c * 16 + g * 4 + r > qrow)) v = 0.f;
                    p[r] = v;
                }
                pk[c][0] = cvtpk(p[0], p[1]);
                pk[c][1] = cvtpk(p[2], p[3]);
            }

            bf16x8 pf[2];
#pragma unroll
            for (int ks = 0; ks < 2; ++ks) {
                uint32_t ylo = pk[2 * ks][0], zlo = pk[2 * ks + 1][0];
                ps32(ylo, zlo); ps16(ylo, zlo);
                uint32_t yhi = pk[2 * ks][1], zhi = pk[2 * ks + 1][1];
                ps32(yhi, zhi); ps16(yhi, zhi);
                union { uint32_t u[4]; bf16x8 v; } fu;
                fu.u[0] = ylo; fu.u[1] = yhi; fu.u[2] = zlo; fu.u[3] = zhi;
                pf[ks] = fu.v;
            }

            __builtin_amdgcn_s_setprio(1);
#pragma unroll
            for (int c2 = 0; c2 < 4; ++c2) {
                o[c2] = __builtin_amdgcn_mfma_f32_16x16x32_bf16(pf[0], vf[0][c2], o[c2], 0, 0, 0);
                o[c2] = __builtin_amdgcn_mfma_f32_16x16x32_bf16(pf[1], vf[1][c2], o[c2], 0, 0, 0);
            }
            // denominator: rowsum via ones-B MFMA (psacc[r] = sum_kv P[q=g*4+r])
            psacc = __builtin_amdgcn_mfma_f32_16x16x32_bf16(pf[0], ones, psacc, 0, 0, 0);
            psacc = __builtin_amdgcn_mfma_f32_16x16x32_bf16(pf[1], ones, psacc, 0, 0, 0);
            __builtin_amdgcn_s_setprio(0);

            __syncthreads();
            buf ^= 1;
        }

        // epilogue: denominators already per-reg in o's layout — no shuffles
        float lrq[4];
#pragma unroll
        for (int r = 0; r < 4; ++r)
            lrq[r] = 1.f / psacc[r];
#pragma unroll
        for (int c2 = 0; c2 < 4; ++c2)
#pragma unroll
            for (int r = 0; r < 4; ++r) {
                const int orow = qw0 + g * 4 + r;
                const int ocol = h * DK_ + c2 * 16 + m16;
                O[((size_t)(b * S_ + orow)) * D_ + ocol] = f2bf(o[c2][r] * lrq[r]);
            }
    }
}

// ---------------- host launcher ----------------
extern "C" void kernel_launch(void* const* d_in, const int* in_sizes, int n_in,
                              void* d_out, int out_size, void* d_ws, size_t ws_size,
                              hipStream_t stream) {
    (void)in_sizes; (void)n_in; (void)out_size; (void)ws_size;
    const float* x   = (const float*)d_in[0];
    const float* Wq  = (const float*)d_in[1];
    const float* Wk  = (const float*)d_in[2];
    const float* Wv  = (const float*)d_in[3];
    const float* Wo  = (const float*)d_in[4];
    const int*   tok = (const int*)d_in[5];

    char* ws = (char*)d_ws;
    const size_t MB = 1u << 20;
    unsigned short* xb  = (unsigned short*)(ws + 0 * MB);   // 8 MB  [4096][1024] bf16
    unsigned short* wqb = (unsigned short*)(ws + 8 * MB);   // 2 MB each
    unsigned short* wkb = (unsigned short*)(ws + 10 * MB);
    unsigned short* wvb = (unsigned short*)(ws + 12 * MB);
    unsigned short* wob = (unsigned short*)(ws + 14 * MB);
    unsigned short* qh  = (unsigned short*)(ws + 16 * MB);  // 8 MB  [bh][s][64]
    unsigned short* kh  = (unsigned short*)(ws + 24 * MB);
    unsigned short* vh  = (unsigned short*)(ws + 32 * MB);  // [bh][64][2048] (V^T)
    unsigned short* ao  = (unsigned short*)(ws + 40 * MB);  // 8 MB  [b][s][1024]
    float2* trig = (float2*)(ws + 40 * MB);  // 512 KB, inside ao region:
    // trig is only read by gemm<0>; ao is written later by fattn. Safe overlap.

    // 1) unified prep: x->bf16, weights->bf16, trig table (one launch)
    k_prep<<<8448, 256, 0, stream>>>(x, Wq, Wk, Wv, Wo,
                                     xb, wqb, wkb, wvb, wob, trig);

    // 2) fused QKV projection -> head layout bf16 (V transposed), RoPE fused
    k_gemm_bt<0><<<dim3(32, 8, 3), 256, 0, stream>>>(
        xb, wqb, wkb, wvb, qh, kh, vh, B_ * S_, D_, D_, tok, trig);

    // 3) causal flash attention -> [b][s][e] bf16
    k_fattn6b<<<dim3(512), 256, 0, stream>>>(qh, kh, vh, ao);

    // 4) output projection -> f32 d_out
    k_gemm_bt<1><<<dim3(32, 8, 1), 256, 0, stream>>>(
        ao, wob, wob, wob, d_out, d_out, d_out, B_ * S_, D_, D_, tok, trig);
}

// Round 13
// 114.725 us; speedup vs baseline: 1.1310x; 1.1310x over previous
//
#include <hip/hip_runtime.h>
#include <stdint.h>

#define B_  2
#define S_  2048
#define D_  1024
#define H_  16
#define DK_ 64

using bf16x8 = __attribute__((ext_vector_type(8))) short;
using f32x4  = __attribute__((ext_vector_type(4))) float;

__device__ __forceinline__ unsigned short f2bf(float f) {
    union { float f; uint32_t u; } v; v.f = f;
    uint32_t r = v.u + 0x7FFFu + ((v.u >> 16) & 1u);
    return (unsigned short)(r >> 16);
}

// pack two f32 -> one u32 of two bf16 (low = s0), RNE in HW
__device__ __forceinline__ uint32_t cvtpk(float lo, float hi) {
    uint32_t r;
    asm("v_cvt_pk_bf16_f32 %0, %1, %2" : "=v"(r) : "v"(lo), "v"(hi));
    return r;
}
// a' = {a(0-31), b(0-31)} ; b' = {a(32-63), b(32-63)}
__device__ __forceinline__ void ps32(uint32_t& a, uint32_t& b) {
    asm volatile("v_permlane32_swap_b32 %0, %1" : "+v"(a), "+v"(b));
}
// 16-lane rows: odd rows of a <-> even rows of b
__device__ __forceinline__ void ps16(uint32_t& a, uint32_t& b) {
    asm volatile("v_permlane16_swap_b32 %0, %1" : "+v"(a), "+v"(b));
}

// async global->LDS, 16B per lane; LDS dest is wave-uniform base + lane*16
#define GLD16(G, L) __builtin_amdgcn_global_load_lds( \
    (const __attribute__((address_space(1))) void*)(const void*)(G), \
    (__attribute__((address_space(3))) void*)(void*)(L), 16, 0, 0)

// ---------------- unified prep: x->bf16 and 4 weights->bf16 ----------------
// grid 8192: [0,4096) x-convert, [4096,8192) weights
__global__ __launch_bounds__(256) void k_prep(
    const float* __restrict__ x,
    const float* __restrict__ Wq, const float* __restrict__ Wk,
    const float* __restrict__ Wv, const float* __restrict__ Wo,
    unsigned short* __restrict__ xb,
    unsigned short* __restrict__ wqb, unsigned short* __restrict__ wkb,
    unsigned short* __restrict__ wvb, unsigned short* __restrict__ wob)
{
    const int bid = blockIdx.x, tid = threadIdx.x;
    const float* s;
    unsigned short* d;
    int i;
    if (bid < 4096) {
        s = x; d = xb; i = bid * 256 + tid;
    } else {
        const int w = (bid - 4096) >> 10;
        s = w == 0 ? Wq : w == 1 ? Wk : w == 2 ? Wv : Wo;
        d = w == 0 ? wqb : w == 1 ? wkb : w == 2 ? wvb : wob;
        i = ((bid - 4096) & 1023) * 256 + tid;
    }
    float4 v = ((const float4*)s)[i];
    union { unsigned short u[4]; uint2 dd; } o;
    o.u[0] = f2bf(v.x); o.u[1] = f2bf(v.y); o.u[2] = f2bf(v.z); o.u[3] = f2bf(v.w);
    ((uint2*)d)[i] = o.dd;
}

// ---------------- GEMM: C[m][n] = sum_k A[m][k] * W[n][k]  (B^T input) ------
// conflict-free XOR swizzle (both-sides) + 2-phase prefetch (round-8 proven).
// MODE 0: bf16 out. z=0 (Q), z=1 (K): [b][h][s][dk] head layout.
//                   z=2 (V): transposed [b][h][dk][s], with the 4 r-values
//                   (4 consecutive s at fixed dk) packed into ONE 8B store.
// MODE 1: f32 out, row-major [m][n] (final output projection)
template<int MODE>
__global__ __launch_bounds__(256) void k_gemm_bt(
    const unsigned short* __restrict__ A,
    const unsigned short* __restrict__ W0,
    const unsigned short* __restrict__ W1,
    const unsigned short* __restrict__ W2,
    void* __restrict__ C0, void* __restrict__ C1, void* __restrict__ C2,
    int M, int N, int K)
{
    __shared__ __align__(16) unsigned short As[2][128 * 32];
    __shared__ __align__(16) unsigned short Bs[2][128 * 32];

    const int tid  = threadIdx.x;
    const int wid  = tid >> 6, lane = tid & 63;
    const int m16  = lane & 15, g = lane >> 4;
    const int m0   = blockIdx.x * 128, n0 = blockIdx.y * 128;
    const unsigned short* Wm = blockIdx.z == 0 ? W0 : (blockIdx.z == 1 ? W1 : W2);
    void* Cm = blockIdx.z == 0 ? C0 : (blockIdx.z == 1 ? C1 : C2);

    const int wm = (wid >> 1) * 64, wn = (wid & 1) * 64;
    const int srow = lane >> 2;
    const int scol = ((lane & 3) ^ ((lane >> 3) & 3)) * 8;
    const int sw8  = (m16 >> 1) & 3;

    const f32x4 fz = {0.f, 0.f, 0.f, 0.f};
    f32x4 acc[4][4];
#pragma unroll
    for (int i = 0; i < 4; ++i)
#pragma unroll
        for (int j = 0; j < 4; ++j) acc[i][j] = fz;

#pragma unroll
    for (int c = 0; c < 2; ++c) {
        const int chunk = wid * 2 + c;
        const int row   = chunk * 16 + srow;
        GLD16(A  + (size_t)(m0 + row) * K + scol, &As[0][chunk * 512]);
        GLD16(Wm + (size_t)(n0 + row) * K + scol, &Bs[0][chunk * 512]);
    }
    __syncthreads();

    int buf = 0;
    for (int k0 = 0; k0 < K; k0 += 32) {
        if (k0 + 32 < K) {
#pragma unroll
            for (int c = 0; c < 2; ++c) {
                const int chunk = wid * 2 + c;
                const int row   = chunk * 16 + srow;
                GLD16(A  + (size_t)(m0 + row) * K + k0 + 32 + scol, &As[buf ^ 1][chunk * 512]);
                GLD16(Wm + (size_t)(n0 + row) * K + k0 + 32 + scol, &Bs[buf ^ 1][chunk * 512]);
            }
        }
        bf16x8 af[4], bf[4];
#pragma unroll
        for (int i = 0; i < 4; ++i)
            af[i] = *(const bf16x8*)(&As[buf][(wm + i * 16 + m16) * 32 + ((g ^ sw8) * 8)]);
#pragma unroll
        for (int j = 0; j < 4; ++j)
            bf[j] = *(const bf16x8*)(&Bs[buf][(wn + j * 16 + m16) * 32 + ((g ^ sw8) * 8)]);
#pragma unroll
        for (int i = 0; i < 4; ++i)
#pragma unroll
            for (int j = 0; j < 4; ++j)
                acc[i][j] = __builtin_amdgcn_mfma_f32_16x16x32_bf16(af[i], bf[j], acc[i][j], 0, 0, 0);
        __syncthreads();
        buf ^= 1;
    }

#pragma unroll
    for (int i = 0; i < 4; ++i) {
#pragma unroll
        for (int j = 0; j < 4; ++j) {
            if (MODE == 1) {
#pragma unroll
                for (int r = 0; r < 4; ++r) {
                    const int row = m0 + wm + i * 16 + g * 4 + r;
                    const int col = n0 + wn + j * 16 + m16;
                    ((float*)Cm)[(size_t)row * N + col] = acc[i][j][r];
                }
            } else if (blockIdx.z == 2) {
                // V: 4 consecutive s at fixed dk -> one aligned 8B store
                const int row0 = m0 + wm + i * 16 + g * 4;
                const int col  = n0 + wn + j * 16 + m16;
                const int b = row0 >> 11, s0 = row0 & (S_ - 1);
                const int h = col >> 6,  dk = col & (DK_ - 1);
                union { unsigned short u[4]; uint2 d; } p4;
#pragma unroll
                for (int r = 0; r < 4; ++r) p4.u[r] = f2bf(acc[i][j][r]);
                *(uint2*)((unsigned short*)Cm
                          + ((size_t)((b * H_ + h) * DK_ + dk)) * S_ + s0) = p4.d;
            } else {
#pragma unroll
                for (int r = 0; r < 4; ++r) {
                    const int row = m0 + wm + i * 16 + g * 4 + r;
                    const int col = n0 + wn + j * 16 + m16;
                    const int b = row >> 11, s = row & (S_ - 1);
                    const int h = col >> 6,  dk = col & (DK_ - 1);
                    ((unsigned short*)Cm)[((size_t)((b * H_ + h) * S_ + s)) * DK_ + dk]
                        = f2bf(acc[i][j][r]);
                }
            }
        }
    }
}

// ---------------- RoPE in place on [bh][s][dk] bf16 buffers ----------------
__global__ __launch_bounds__(256) void k_rope_inplace(
    unsigned short* __restrict__ qh, unsigned short* __restrict__ kh,
    const int* __restrict__ tok)
{
    const int idx = blockIdx.x * 256 + threadIdx.x;
    const int c = idx & 7;
    const int s = (idx >> 3) & (S_ - 1);
    const int b = idx >> 18;
    const size_t off = (size_t)idx * 8;

    const float pos = (float)tok[b * S_ + s];
    float cs[4], sn[4];
#pragma unroll
    for (int i = 0; i < 4; ++i) {
        const int p = c * 4 + i;
        const float inv = exp2f((float)(-2 * p) * (13.287712379549449f / 64.f));
        sincosf(pos * inv, &sn[i], &cs[i]);
    }
    bf16x8 qv = *(bf16x8*)(qh + off);
    bf16x8 kv = *(bf16x8*)(kh + off);
    bf16x8 qo, ko;
#pragma unroll
    for (int i = 0; i < 4; ++i) {
        union { uint32_t u; float f; } q1{(uint32_t)(unsigned short)qv[2*i] << 16};
        union { uint32_t u; float f; } q2{(uint32_t)(unsigned short)qv[2*i+1] << 16};
        qo[2 * i]     = (short)f2bf(q1.f * cs[i] - q2.f * sn[i]);
        qo[2 * i + 1] = (short)f2bf(q1.f * sn[i] + q2.f * cs[i]);
        union { uint32_t u; float f; } k1{(uint32_t)(unsigned short)kv[2*i] << 16};
        union { uint32_t u; float f; } k2{(uint32_t)(unsigned short)kv[2*i+1] << 16};
        ko[2 * i]     = (short)f2bf(k1.f * cs[i] - k2.f * sn[i]);
        ko[2 * i + 1] = (short)f2bf(k1.f * sn[i] + k2.f * cs[i]);
    }
    *(bf16x8*)(qh + off) = qo;
    *(bf16x8*)(kh + off) = ko;
}

// ---------------- causal flash attention v6b (round-12, kept) ----------------
// v6 (16-row waves, 64-kv tiles, uniform fold j/31-j, dbuf + __syncthreads,
// permlane P, V-frag hoist) + ones-MFMA row-sum: softmax denominator
// accumulated by 2 extra PV MFMAs against an all-ones B fragment — row-sums
// land per-reg in o's C-layout, zero cross-lane ops.
__global__ __launch_bounds__(256, 2) void k_fattn6b(
    const unsigned short* __restrict__ Q,   // [bh][s][64]
    const unsigned short* __restrict__ K,   // [bh][s][64]
    const unsigned short* __restrict__ Vt,  // [bh][64][2048]
    unsigned short* __restrict__ O)         // [b][s][1024] bf16
{
    __shared__ __align__(16) unsigned short Ks[2][64 * 64];
    __shared__ __align__(16) unsigned short Vs[2][64 * 64];

    const int tid = threadIdx.x, wid = tid >> 6, lane = tid & 63;
    const int m16 = lane & 15, g = lane >> 4;
    const int bh = blockIdx.x & 31;
    const int j  = blockIdx.x >> 5;                     // 0..15
    const int b = bh >> 4, h = bh & 15;
    const unsigned short* Qb = Q  + (size_t)bh * S_ * DK_;
    const unsigned short* Kb = K  + (size_t)bh * S_ * DK_;
    const unsigned short* Vb = Vt + (size_t)bh * DK_ * S_;

    const int r8   = lane >> 3;
    const int slot = (lane & 7) ^ r8;
    const int ch0  = wid * 2, ch1 = wid * 2 + 1;

    const f32x4 fz = {0.f, 0.f, 0.f, 0.f};
    const float kSc = 0.125f * 1.4426950408889634f;
    union { uint32_t u[4]; bf16x8 v; } one_;
    one_.u[0] = one_.u[1] = one_.u[2] = one_.u[3] = 0x3F803F80u;
    const bf16x8 ones = one_.v;

    GLD16(Kb + (size_t)(ch0 * 8 + r8) * DK_ + slot * 8, &Ks[0][ch0 * 512]);
    GLD16(Kb + (size_t)(ch1 * 8 + r8) * DK_ + slot * 8, &Ks[0][ch1 * 512]);
    GLD16(Vb + (size_t)(ch0 * 8 + r8) * S_  + slot * 8, &Vs[0][ch0 * 512]);
    GLD16(Vb + (size_t)(ch1 * 8 + r8) * S_  + slot * 8, &Vs[0][ch1 * 512]);
    __syncthreads();

    int buf = 0;
#pragma unroll
    for (int ph = 0; ph < 2; ++ph) {
        const int qi = ph ? 31 - j : j;
        const int q0 = qi * 64;
        const int qw0 = q0 + wid * 16;

        bf16x8 qf[2];
        {
            const unsigned short* qp = Qb + (size_t)(qw0 + m16) * DK_ + g * 8;
            qf[0] = *(const bf16x8*)(qp);
            qf[1] = *(const bf16x8*)(qp + 32);
        }

        f32x4 o[4];
#pragma unroll
        for (int i = 0; i < 4; ++i) o[i] = fz;
        f32x4 psacc = fz;               // row-sum accumulator (ones-MFMA)

        const int nt = qi + 1;
        for (int t = 0; t < nt; ++t) {
            const int kv0 = t * 64;
            int nkv0 = -1;
            if (t + 1 < nt)      nkv0 = kv0 + 64;
            else if (ph == 0)    nkv0 = 0;
            if (nkv0 >= 0) {
                GLD16(Kb + (size_t)(nkv0 + ch0 * 8 + r8) * DK_ + slot * 8, &Ks[buf ^ 1][ch0 * 512]);
                GLD16(Kb + (size_t)(nkv0 + ch1 * 8 + r8) * DK_ + slot * 8, &Ks[buf ^ 1][ch1 * 512]);
                GLD16(Vb + (size_t)(ch0 * 8 + r8) * S_ + nkv0 + slot * 8, &Vs[buf ^ 1][ch0 * 512]);
                GLD16(Vb + (size_t)(ch1 * 8 + r8) * S_ + nkv0 + slot * 8, &Vs[buf ^ 1][ch1 * 512]);
            }

            f32x4 sc[4];
            __builtin_amdgcn_s_setprio(1);
#pragma unroll
            for (int c = 0; c < 4; ++c) {
                const int row = c * 16 + m16, rr = row & 7;
                bf16x8 kf0 = *(const bf16x8*)(&Ks[buf][row * 64 + ((g ^ rr) << 3)]);
                bf16x8 kf1 = *(const bf16x8*)(&Ks[buf][row * 64 + (((4 + g) ^ rr) << 3)]);
                f32x4 z = fz;
                z = __builtin_amdgcn_mfma_f32_16x16x32_bf16(kf0, qf[0], z, 0, 0, 0);
                z = __builtin_amdgcn_mfma_f32_16x16x32_bf16(kf1, qf[1], z, 0, 0, 0);
                sc[c] = z;
            }
            __builtin_amdgcn_s_setprio(0);

            bf16x8 vf[2][4];
#pragma unroll
            for (int c2 = 0; c2 < 4; ++c2) {
                const int rv = (c2 * 16 + m16) & 7;
                vf[0][c2] = *(const bf16x8*)(&Vs[buf][(c2 * 16 + m16) * 64 + ((g ^ rv) << 3)]);
                vf[1][c2] = *(const bf16x8*)(&Vs[buf][(c2 * 16 + m16) * 64 + (((4 + g) ^ rv) << 3)]);
            }

            const bool maskT = (t == qi);
            const int qrow = qw0 + m16;
            uint32_t pk[4][2];
#pragma unroll
            for (int c = 0; c < 4; ++c) {
                float p[4];
#pragma unroll
                for (int r = 0; r < 4; ++r) {
                    float v = exp2f(sc[c][r] * kSc);
                    if (maskT && (kv0 + c * 16 + g * 4 + r > qrow)) v = 0.f;
                    p[r] = v;
                }
                pk[c][0] = cvtpk(p[0], p[1]);
                pk[c][1] = cvtpk(p[2], p[3]);
            }

            bf16x8 pf[2];
#pragma unroll
            for (int ks = 0; ks < 2; ++ks) {
                uint32_t ylo = pk[2 * ks][0], zlo = pk[2 * ks + 1][0];
                ps32(ylo, zlo); ps16(ylo, zlo);
                uint32_t yhi = pk[2 * ks][1], zhi = pk[2 * ks + 1][1];
                ps32(yhi, zhi); ps16(yhi, zhi);
                union { uint32_t u[4]; bf16x8 v; } fu;
                fu.u[0] = ylo; fu.u[1] = yhi; fu.u[2] = zlo; fu.u[3] = zhi;
                pf[ks] = fu.v;
            }

            __builtin_amdgcn_s_setprio(1);
#pragma unroll
            for (int c2 = 0; c2 < 4; ++c2) {
                o[c2] = __builtin_amdgcn_mfma_f32_16x16x32_bf16(pf[0], vf[0][c2], o[c2], 0, 0, 0);
                o[c2] = __builtin_amdgcn_mfma_f32_16x16x32_bf16(pf[1], vf[1][c2], o[c2], 0, 0, 0);
            }
            // denominator: rowsum via ones-B MFMA (psacc[r] = sum_kv P[q=g*4+r])
            psacc = __builtin_amdgcn_mfma_f32_16x16x32_bf16(pf[0], ones, psacc, 0, 0, 0);
            psacc = __builtin_amdgcn_mfma_f32_16x16x32_bf16(pf[1], ones, psacc, 0, 0, 0);
            __builtin_amdgcn_s_setprio(0);

            __syncthreads();
            buf ^= 1;
        }

        // epilogue: denominators already per-reg in o's layout — no shuffles
        float lrq[4];
#pragma unroll
        for (int r = 0; r < 4; ++r)
            lrq[r] = 1.f / psacc[r];
#pragma unroll
        for (int c2 = 0; c2 < 4; ++c2)
#pragma unroll
            for (int r = 0; r < 4; ++r) {
                const int orow = qw0 + g * 4 + r;
                const int ocol = h * DK_ + c2 * 16 + m16;
                O[((size_t)(b * S_ + orow)) * D_ + ocol] = f2bf(o[c2][r] * lrq[r]);
            }
    }
}

// ---------------- host launcher ----------------
extern "C" void kernel_launch(void* const* d_in, const int* in_sizes, int n_in,
                              void* d_out, int out_size, void* d_ws, size_t ws_size,
                              hipStream_t stream) {
    (void)in_sizes; (void)n_in; (void)out_size; (void)ws_size;
    const float* x   = (const float*)d_in[0];
    const float* Wq  = (const float*)d_in[1];
    const float* Wk  = (const float*)d_in[2];
    const float* Wv  = (const float*)d_in[3];
    const float* Wo  = (const float*)d_in[4];
    const int*   tok = (const int*)d_in[5];

    char* ws = (char*)d_ws;
    const size_t MB = 1u << 20;
    unsigned short* xb  = (unsigned short*)(ws + 0 * MB);   // 8 MB  [4096][1024] bf16
    unsigned short* wqb = (unsigned short*)(ws + 8 * MB);   // 2 MB each
    unsigned short* wkb = (unsigned short*)(ws + 10 * MB);
    unsigned short* wvb = (unsigned short*)(ws + 12 * MB);
    unsigned short* wob = (unsigned short*)(ws + 14 * MB);
    unsigned short* qh  = (unsigned short*)(ws + 16 * MB);  // 8 MB  [bh][s][64]
    unsigned short* kh  = (unsigned short*)(ws + 24 * MB);
    unsigned short* vh  = (unsigned short*)(ws + 32 * MB);  // [bh][64][2048] (V^T)
    unsigned short* ao  = (unsigned short*)(ws + 40 * MB);  // 8 MB  [b][s][1024]

    // 1) unified prep: x->bf16, weights->bf16 (one launch)
    k_prep<<<8192, 256, 0, stream>>>(x, Wq, Wk, Wv, Wo,
                                     xb, wqb, wkb, wvb, wob);

    // 2) fused QKV projection -> head layout bf16 (V transposed, packed store)
    k_gemm_bt<0><<<dim3(32, 8, 3), 256, 0, stream>>>(
        xb, wqb, wkb, wvb, qh, kh, vh, B_ * S_, D_, D_);

    // 3) RoPE in place on Q,K
    k_rope_inplace<<<2048, 256, 0, stream>>>(qh, kh, tok);

    // 4) causal flash attention -> [b][s][e] bf16
    k_fattn6b<<<dim3(512), 256, 0, stream>>>(qh, kh, vh, ao);

    // 5) output projection -> f32 d_out
    k_gemm_bt<1><<<dim3(32, 8, 1), 256, 0, stream>>>(
        ao, wob, wob, wob, d_out, d_out, d_out, B_ * S_, D_, D_);
}

// Round 14
// 109.934 us; speedup vs baseline: 1.1803x; 1.0436x over previous
//
#include <hip/hip_runtime.h>
#include <stdint.h>

#define B_  2
#define S_  2048
#define D_  1024
#define H_  16
#define DK_ 64

using bf16x8 = __attribute__((ext_vector_type(8))) short;
using f32x4  = __attribute__((ext_vector_type(4))) float;

__device__ __forceinline__ unsigned short f2bf(float f) {
    union { float f; uint32_t u; } v; v.f = f;
    uint32_t r = v.u + 0x7FFFu + ((v.u >> 16) & 1u);
    return (unsigned short)(r >> 16);
}

// pack two f32 -> one u32 of two bf16 (low = s0), RNE in HW
__device__ __forceinline__ uint32_t cvtpk(float lo, float hi) {
    uint32_t r;
    asm("v_cvt_pk_bf16_f32 %0, %1, %2" : "=v"(r) : "v"(lo), "v"(hi));
    return r;
}
// a' = {a(0-31), b(0-31)} ; b' = {a(32-63), b(32-63)}
__device__ __forceinline__ void ps32(uint32_t& a, uint32_t& b) {
    asm volatile("v_permlane32_swap_b32 %0, %1" : "+v"(a), "+v"(b));
}
// 16-lane rows: odd rows of a <-> even rows of b
__device__ __forceinline__ void ps16(uint32_t& a, uint32_t& b) {
    asm volatile("v_permlane16_swap_b32 %0, %1" : "+v"(a), "+v"(b));
}

// async global->LDS, 16B per lane; LDS dest is wave-uniform base + lane*16
#define GLD16(G, L) __builtin_amdgcn_global_load_lds( \
    (const __attribute__((address_space(1))) void*)(const void*)(G), \
    (__attribute__((address_space(3))) void*)(void*)(L), 16, 0, 0)

// ---------------- unified prep: x->bf16 and 4 weights->bf16 ----------------
// grid 8192: [0,4096) x-convert, [4096,8192) weights
__global__ __launch_bounds__(256) void k_prep(
    const float* __restrict__ x,
    const float* __restrict__ Wq, const float* __restrict__ Wk,
    const float* __restrict__ Wv, const float* __restrict__ Wo,
    unsigned short* __restrict__ xb,
    unsigned short* __restrict__ wqb, unsigned short* __restrict__ wkb,
    unsigned short* __restrict__ wvb, unsigned short* __restrict__ wob)
{
    const int bid = blockIdx.x, tid = threadIdx.x;
    const float* s;
    unsigned short* d;
    int i;
    if (bid < 4096) {
        s = x; d = xb; i = bid * 256 + tid;
    } else {
        const int w = (bid - 4096) >> 10;
        s = w == 0 ? Wq : w == 1 ? Wk : w == 2 ? Wv : Wo;
        d = w == 0 ? wqb : w == 1 ? wkb : w == 2 ? wvb : wob;
        i = ((bid - 4096) & 1023) * 256 + tid;
    }
    float4 v = ((const float4*)s)[i];
    union { unsigned short u[4]; uint2 dd; } o;
    o.u[0] = f2bf(v.x); o.u[1] = f2bf(v.y); o.u[2] = f2bf(v.z); o.u[3] = f2bf(v.w);
    ((uint2*)d)[i] = o.dd;
}

// ---------------- GEMM: C[m][n] = sum_k A[m][k] * W[n][k]  (B^T input) ------
// conflict-free XOR swizzle (both-sides) + 2-phase prefetch (round-8 proven).
// TM = tile M (128 or 64). TM=64 doubles blocks -> 2 blocks/CU for the
// N=1024 output projection (was 1 block/CU = 1 wave/SIMD, latency-starved).
// MODE 0: bf16 out. z=0 (Q), z=1 (K): [b][h][s][dk] head layout.
//                   z=2 (V): transposed [b][h][dk][s], packed 8B stores.
// MODE 1: f32 out, row-major [m][n] (final output projection)
template<int MODE, int TM>
__global__ __launch_bounds__(256) void k_gemm_bt(
    const unsigned short* __restrict__ A,
    const unsigned short* __restrict__ W0,
    const unsigned short* __restrict__ W1,
    const unsigned short* __restrict__ W2,
    void* __restrict__ C0, void* __restrict__ C1, void* __restrict__ C2,
    int M, int N, int K)
{
    constexpr int MI  = TM / 32;       // m-frags per wave (128->4, 64->2)
    constexpr int ACH = TM / 64;       // A chunks staged per wave
    __shared__ __align__(16) unsigned short As[2][TM * 32];
    __shared__ __align__(16) unsigned short Bs[2][128 * 32];

    const int tid  = threadIdx.x;
    const int wid  = tid >> 6, lane = tid & 63;
    const int m16  = lane & 15, g = lane >> 4;
    const int m0   = blockIdx.x * TM, n0 = blockIdx.y * 128;
    const unsigned short* Wm = blockIdx.z == 0 ? W0 : (blockIdx.z == 1 ? W1 : W2);
    void* Cm = blockIdx.z == 0 ? C0 : (blockIdx.z == 1 ? C1 : C2);

    const int wm = (wid >> 1) * (TM / 2), wn = (wid & 1) * 64;
    const int srow = lane >> 2;
    const int scol = ((lane & 3) ^ ((lane >> 3) & 3)) * 8;
    const int sw8  = (m16 >> 1) & 3;

    const f32x4 fz = {0.f, 0.f, 0.f, 0.f};
    f32x4 acc[MI][4];
#pragma unroll
    for (int i = 0; i < MI; ++i)
#pragma unroll
        for (int j = 0; j < 4; ++j) acc[i][j] = fz;

#pragma unroll
    for (int c = 0; c < ACH; ++c) {
        const int chunk = wid * ACH + c;
        GLD16(A + (size_t)(m0 + chunk * 16 + srow) * K + scol, &As[0][chunk * 512]);
    }
#pragma unroll
    for (int c = 0; c < 2; ++c) {
        const int chunk = wid * 2 + c;
        GLD16(Wm + (size_t)(n0 + chunk * 16 + srow) * K + scol, &Bs[0][chunk * 512]);
    }
    __syncthreads();

    int buf = 0;
    for (int k0 = 0; k0 < K; k0 += 32) {
        if (k0 + 32 < K) {
#pragma unroll
            for (int c = 0; c < ACH; ++c) {
                const int chunk = wid * ACH + c;
                GLD16(A + (size_t)(m0 + chunk * 16 + srow) * K + k0 + 32 + scol,
                      &As[buf ^ 1][chunk * 512]);
            }
#pragma unroll
            for (int c = 0; c < 2; ++c) {
                const int chunk = wid * 2 + c;
                GLD16(Wm + (size_t)(n0 + chunk * 16 + srow) * K + k0 + 32 + scol,
                      &Bs[buf ^ 1][chunk * 512]);
            }
        }
        bf16x8 af[MI], bf[4];
#pragma unroll
        for (int i = 0; i < MI; ++i)
            af[i] = *(const bf16x8*)(&As[buf][(wm + i * 16 + m16) * 32 + ((g ^ sw8) * 8)]);
#pragma unroll
        for (int j = 0; j < 4; ++j)
            bf[j] = *(const bf16x8*)(&Bs[buf][(wn + j * 16 + m16) * 32 + ((g ^ sw8) * 8)]);
#pragma unroll
        for (int i = 0; i < MI; ++i)
#pragma unroll
            for (int j = 0; j < 4; ++j)
                acc[i][j] = __builtin_amdgcn_mfma_f32_16x16x32_bf16(af[i], bf[j], acc[i][j], 0, 0, 0);
        __syncthreads();
        buf ^= 1;
    }

#pragma unroll
    for (int i = 0; i < MI; ++i) {
#pragma unroll
        for (int j = 0; j < 4; ++j) {
            if (MODE == 1) {
#pragma unroll
                for (int r = 0; r < 4; ++r) {
                    const int row = m0 + wm + i * 16 + g * 4 + r;
                    const int col = n0 + wn + j * 16 + m16;
                    ((float*)Cm)[(size_t)row * N + col] = acc[i][j][r];
                }
            } else if (blockIdx.z == 2) {
                // V: 4 consecutive s at fixed dk -> one aligned 8B store
                const int row0 = m0 + wm + i * 16 + g * 4;
                const int col  = n0 + wn + j * 16 + m16;
                const int b = row0 >> 11, s0 = row0 & (S_ - 1);
                const int h = col >> 6,  dk = col & (DK_ - 1);
                union { unsigned short u[4]; uint2 d; } p4;
#pragma unroll
                for (int r = 0; r < 4; ++r) p4.u[r] = f2bf(acc[i][j][r]);
                *(uint2*)((unsigned short*)Cm
                          + ((size_t)((b * H_ + h) * DK_ + dk)) * S_ + s0) = p4.d;
            } else {
#pragma unroll
                for (int r = 0; r < 4; ++r) {
                    const int row = m0 + wm + i * 16 + g * 4 + r;
                    const int col = n0 + wn + j * 16 + m16;
                    const int b = row >> 11, s = row & (S_ - 1);
                    const int h = col >> 6,  dk = col & (DK_ - 1);
                    ((unsigned short*)Cm)[((size_t)((b * H_ + h) * S_ + s)) * DK_ + dk]
                        = f2bf(acc[i][j][r]);
                }
            }
        }
    }
}

// ---------------- RoPE in place on [bh][s][dk] bf16 buffers ----------------
// Q additionally scaled by 0.125*log2(e) so fattn's softmax is a bare exp2.
__global__ __launch_bounds__(256) void k_rope_inplace(
    unsigned short* __restrict__ qh, unsigned short* __restrict__ kh,
    const int* __restrict__ tok)
{
    const int idx = blockIdx.x * 256 + threadIdx.x;
    const int c = idx & 7;
    const int s = (idx >> 3) & (S_ - 1);
    const int b = idx >> 18;
    const size_t off = (size_t)idx * 8;
    const float SC = 0.18033688011112042f;   // 0.125 * log2(e), folded into Q

    const float pos = (float)tok[b * S_ + s];
    float cs[4], sn[4];
#pragma unroll
    for (int i = 0; i < 4; ++i) {
        const int p = c * 4 + i;
        const float inv = exp2f((float)(-2 * p) * (13.287712379549449f / 64.f));
        sincosf(pos * inv, &sn[i], &cs[i]);
    }
    bf16x8 qv = *(bf16x8*)(qh + off);
    bf16x8 kv = *(bf16x8*)(kh + off);
    bf16x8 qo, ko;
#pragma unroll
    for (int i = 0; i < 4; ++i) {
        union { uint32_t u; float f; } q1{(uint32_t)(unsigned short)qv[2*i] << 16};
        union { uint32_t u; float f; } q2{(uint32_t)(unsigned short)qv[2*i+1] << 16};
        qo[2 * i]     = (short)f2bf((q1.f * cs[i] - q2.f * sn[i]) * SC);
        qo[2 * i + 1] = (short)f2bf((q1.f * sn[i] + q2.f * cs[i]) * SC);
        union { uint32_t u; float f; } k1{(uint32_t)(unsigned short)kv[2*i] << 16};
        union { uint32_t u; float f; } k2{(uint32_t)(unsigned short)kv[2*i+1] << 16};
        ko[2 * i]     = (short)f2bf(k1.f * cs[i] - k2.f * sn[i]);
        ko[2 * i + 1] = (short)f2bf(k1.f * sn[i] + k2.f * cs[i]);
    }
    *(bf16x8*)(qh + off) = qo;
    *(bf16x8*)(kh + off) = ko;
}

// ---------------- causal flash attention v6c ----------------
// v6b (16-row waves, 64-kv tiles, uniform fold j/31-j, dbuf + __syncthreads,
// permlane P, V-frag hoist, ones-MFMA row-sum) with the softmax scale
// pre-folded into Q at rope time: inner loop exp is a bare exp2f (16 fewer
// v_mul per wave-tile on the busiest pipe).
__global__ __launch_bounds__(256, 2) void k_fattn6c(
    const unsigned short* __restrict__ Q,   // [bh][s][64] (pre-scaled)
    const unsigned short* __restrict__ K,   // [bh][s][64]
    const unsigned short* __restrict__ Vt,  // [bh][64][2048]
    unsigned short* __restrict__ O)         // [b][s][1024] bf16
{
    __shared__ __align__(16) unsigned short Ks[2][64 * 64];
    __shared__ __align__(16) unsigned short Vs[2][64 * 64];

    const int tid = threadIdx.x, wid = tid >> 6, lane = tid & 63;
    const int m16 = lane & 15, g = lane >> 4;
    const int bh = blockIdx.x & 31;
    const int j  = blockIdx.x >> 5;                     // 0..15
    const int b = bh >> 4, h = bh & 15;
    const unsigned short* Qb = Q  + (size_t)bh * S_ * DK_;
    const unsigned short* Kb = K  + (size_t)bh * S_ * DK_;
    const unsigned short* Vb = Vt + (size_t)bh * DK_ * S_;

    const int r8   = lane >> 3;
    const int slot = (lane & 7) ^ r8;
    const int ch0  = wid * 2, ch1 = wid * 2 + 1;

    const f32x4 fz = {0.f, 0.f, 0.f, 0.f};
    union { uint32_t u[4]; bf16x8 v; } one_;
    one_.u[0] = one_.u[1] = one_.u[2] = one_.u[3] = 0x3F803F80u;
    const bf16x8 ones = one_.v;

    GLD16(Kb + (size_t)(ch0 * 8 + r8) * DK_ + slot * 8, &Ks[0][ch0 * 512]);
    GLD16(Kb + (size_t)(ch1 * 8 + r8) * DK_ + slot * 8, &Ks[0][ch1 * 512]);
    GLD16(Vb + (size_t)(ch0 * 8 + r8) * S_  + slot * 8, &Vs[0][ch0 * 512]);
    GLD16(Vb + (size_t)(ch1 * 8 + r8) * S_  + slot * 8, &Vs[0][ch1 * 512]);
    __syncthreads();

    int buf = 0;
#pragma unroll
    for (int ph = 0; ph < 2; ++ph) {
        const int qi = ph ? 31 - j : j;
        const int q0 = qi * 64;
        const int qw0 = q0 + wid * 16;

        bf16x8 qf[2];
        {
            const unsigned short* qp = Qb + (size_t)(qw0 + m16) * DK_ + g * 8;
            qf[0] = *(const bf16x8*)(qp);
            qf[1] = *(const bf16x8*)(qp + 32);
        }

        f32x4 o[4];
#pragma unroll
        for (int i = 0; i < 4; ++i) o[i] = fz;
        f32x4 psacc = fz;               // row-sum accumulator (ones-MFMA)

        const int nt = qi + 1;
        for (int t = 0; t < nt; ++t) {
            const int kv0 = t * 64;
            int nkv0 = -1;
            if (t + 1 < nt)      nkv0 = kv0 + 64;
            else if (ph == 0)    nkv0 = 0;
            if (nkv0 >= 0) {
                GLD16(Kb + (size_t)(nkv0 + ch0 * 8 + r8) * DK_ + slot * 8, &Ks[buf ^ 1][ch0 * 512]);
                GLD16(Kb + (size_t)(nkv0 + ch1 * 8 + r8) * DK_ + slot * 8, &Ks[buf ^ 1][ch1 * 512]);
                GLD16(Vb + (size_t)(ch0 * 8 + r8) * S_ + nkv0 + slot * 8, &Vs[buf ^ 1][ch0 * 512]);
                GLD16(Vb + (size_t)(ch1 * 8 + r8) * S_ + nkv0 + slot * 8, &Vs[buf ^ 1][ch1 * 512]);
            }

            f32x4 sc[4];
            __builtin_amdgcn_s_setprio(1);
#pragma unroll
            for (int c = 0; c < 4; ++c) {
                const int row = c * 16 + m16, rr = row & 7;
                bf16x8 kf0 = *(const bf16x8*)(&Ks[buf][row * 64 + ((g ^ rr) << 3)]);
                bf16x8 kf1 = *(const bf16x8*)(&Ks[buf][row * 64 + (((4 + g) ^ rr) << 3)]);
                f32x4 z = fz;
                z = __builtin_amdgcn_mfma_f32_16x16x32_bf16(kf0, qf[0], z, 0, 0, 0);
                z = __builtin_amdgcn_mfma_f32_16x16x32_bf16(kf1, qf[1], z, 0, 0, 0);
                sc[c] = z;
            }
            __builtin_amdgcn_s_setprio(0);

            bf16x8 vf[2][4];
#pragma unroll
            for (int c2 = 0; c2 < 4; ++c2) {
                const int rv = (c2 * 16 + m16) & 7;
                vf[0][c2] = *(const bf16x8*)(&Vs[buf][(c2 * 16 + m16) * 64 + ((g ^ rv) << 3)]);
                vf[1][c2] = *(const bf16x8*)(&Vs[buf][(c2 * 16 + m16) * 64 + (((4 + g) ^ rv) << 3)]);
            }

            const bool maskT = (t == qi);
            const int qrow = qw0 + m16;
            uint32_t pk[4][2];
#pragma unroll
            for (int c = 0; c < 4; ++c) {
                float p[4];
#pragma unroll
                for (int r = 0; r < 4; ++r) {
                    float v = exp2f(sc[c][r]);        // scale pre-folded into Q
                    if (maskT && (kv0 + c * 16 + g * 4 + r > qrow)) v = 0.f;
                    p[r] = v;
                }
                pk[c][0] = cvtpk(p[0], p[1]);
                pk[c][1] = cvtpk(p[2], p[3]);
            }

            bf16x8 pf[2];
#pragma unroll
            for (int ks = 0; ks < 2; ++ks) {
                uint32_t ylo = pk[2 * ks][0], zlo = pk[2 * ks + 1][0];
                ps32(ylo, zlo); ps16(ylo, zlo);
                uint32_t yhi = pk[2 * ks][1], zhi = pk[2 * ks + 1][1];
                ps32(yhi, zhi); ps16(yhi, zhi);
                union { uint32_t u[4]; bf16x8 v; } fu;
                fu.u[0] = ylo; fu.u[1] = yhi; fu.u[2] = zlo; fu.u[3] = zhi;
                pf[ks] = fu.v;
            }

            __builtin_amdgcn_s_setprio(1);
#pragma unroll
            for (int c2 = 0; c2 < 4; ++c2) {
                o[c2] = __builtin_amdgcn_mfma_f32_16x16x32_bf16(pf[0], vf[0][c2], o[c2], 0, 0, 0);
                o[c2] = __builtin_amdgcn_mfma_f32_16x16x32_bf16(pf[1], vf[1][c2], o[c2], 0, 0, 0);
            }
            // denominator: rowsum via ones-B MFMA (psacc[r] = sum_kv P[q=g*4+r])
            psacc = __builtin_amdgcn_mfma_f32_16x16x32_bf16(pf[0], ones, psacc, 0, 0, 0);
            psacc = __builtin_amdgcn_mfma_f32_16x16x32_bf16(pf[1], ones, psacc, 0, 0, 0);
            __builtin_amdgcn_s_setprio(0);

            __syncthreads();
            buf ^= 1;
        }

        // epilogue: denominators already per-reg in o's layout — no shuffles
        float lrq[4];
#pragma unroll
        for (int r = 0; r < 4; ++r)
            lrq[r] = 1.f / psacc[r];
#pragma unroll
        for (int c2 = 0; c2 < 4; ++c2)
#pragma unroll
            for (int r = 0; r < 4; ++r) {
                const int orow = qw0 + g * 4 + r;
                const int ocol = h * DK_ + c2 * 16 + m16;
                O[((size_t)(b * S_ + orow)) * D_ + ocol] = f2bf(o[c2][r] * lrq[r]);
            }
    }
}

// ---------------- host launcher ----------------
extern "C" void kernel_launch(void* const* d_in, const int* in_sizes, int n_in,
                              void* d_out, int out_size, void* d_ws, size_t ws_size,
                              hipStream_t stream) {
    (void)in_sizes; (void)n_in; (void)out_size; (void)ws_size;
    const float* x   = (const float*)d_in[0];
    const float* Wq  = (const float*)d_in[1];
    const float* Wk  = (const float*)d_in[2];
    const float* Wv  = (const float*)d_in[3];
    const float* Wo  = (const float*)d_in[4];
    const int*   tok = (const int*)d_in[5];

    char* ws = (char*)d_ws;
    const size_t MB = 1u << 20;
    unsigned short* xb  = (unsigned short*)(ws + 0 * MB);   // 8 MB  [4096][1024] bf16
    unsigned short* wqb = (unsigned short*)(ws + 8 * MB);   // 2 MB each
    unsigned short* wkb = (unsigned short*)(ws + 10 * MB);
    unsigned short* wvb = (unsigned short*)(ws + 12 * MB);
    unsigned short* wob = (unsigned short*)(ws + 14 * MB);
    unsigned short* qh  = (unsigned short*)(ws + 16 * MB);  // 8 MB  [bh][s][64]
    unsigned short* kh  = (unsigned short*)(ws + 24 * MB);
    unsigned short* vh  = (unsigned short*)(ws + 32 * MB);  // [bh][64][2048] (V^T)
    unsigned short* ao  = (unsigned short*)(ws + 40 * MB);  // 8 MB  [b][s][1024]

    // 1) unified prep: x->bf16, weights->bf16 (one launch)
    k_prep<<<8192, 256, 0, stream>>>(x, Wq, Wk, Wv, Wo,
                                     xb, wqb, wkb, wvb, wob);

    // 2) fused QKV projection -> head layout bf16 (V transposed, packed store)
    k_gemm_bt<0, 128><<<dim3(32, 8, 3), 256, 0, stream>>>(
        xb, wqb, wkb, wvb, qh, kh, vh, B_ * S_, D_, D_);

    // 3) RoPE in place on Q,K (softmax scale folded into Q)
    k_rope_inplace<<<2048, 256, 0, stream>>>(qh, kh, tok);

    // 4) causal flash attention -> [b][s][e] bf16
    k_fattn6c<<<dim3(512), 256, 0, stream>>>(qh, kh, vh, ao);

    // 5) output projection -> f32 d_out (TM=64: 512 blocks, 2/CU)
    k_gemm_bt<1, 64><<<dim3(64, 8, 1), 256, 0, stream>>>(
        ao, wob, wob, wob, d_out, d_out, d_out, B_ * S_, D_, D_);
}